// Round 2
// baseline (114.041 us; speedup 1.0000x reference)
//
#include <hip/hip_runtime.h>
#include <hip/hip_bf16.h>
#include <math.h>

#define N 8192
#define D 256
#define MARGIN 0.3f
#define EPS 1e-12f

#define BT 128                             // block tile (i and j)
#define NJB (N / BT)                       // 64 tile-blocks per dim
#define TOTAL_TRI (NJB * (NJB + 1) / 2)    // 2080 upper-triangle tiles = 8 * 260

typedef __attribute__((ext_vector_type(8))) short short8;   // 8 bf16 in 4 VGPRs
typedef __attribute__((ext_vector_type(4))) float floatx4;  // MFMA C/D

static __device__ inline ushort f2bf(float f) {
    __hip_bfloat16 h = __float2bfloat16(f);
    return *reinterpret_cast<ushort*>(&h);
}

// Raw barrier: no implicit vmcnt(0) drain (unlike __syncthreads), compiler fences on both sides.
#define BARRIER() do { asm volatile("" ::: "memory"); __builtin_amdgcn_s_barrier(); asm volatile("" ::: "memory"); } while (0)
#define WAITVM(n) asm volatile("s_waitcnt vmcnt(" #n ")" ::: "memory")

// global->LDS direct (16B/lane): global addr is per-lane, LDS dest is wave-uniform base + lane*16.
static __device__ inline void gload_lds16(const ushort* g, ushort* l) {
    __builtin_amdgcn_global_load_lds((const __attribute__((address_space(1))) void*)g,
                                     (__attribute__((address_space(3))) void*)l, 16, 0, 0);
}

// fn16t layout (MFMA-fragment-tiled): element (row r, k) lives at
//   chunk c = (r>>4)*8 + (k>>5), offset (((k>>3)&3)*16 + (r&15))*8 + (k&7)
// so one 1KB chunk = one wave-wide 16B/lane transaction.

// ---------------- Kernel 1: L2 normalize -> bf16 in tiled layout (16 rows/block) -------------
__global__ __launch_bounds__(256) void normalize_kernel(const float* __restrict__ x,
                                                        ushort* __restrict__ fn16t,
                                                        float* __restrict__ out) {
    __shared__ ushort lnorm[16][256];     // 8 KB
    const int g    = blockIdx.x;          // group of 16 rows
    const int t    = threadIdx.x;
    const int w    = t >> 6;
    const int lane = t & 63;
    if (g == 0 && t == 0) out[0] = 0.0f;

    #pragma unroll
    for (int rr = 0; rr < 4; rr++) {
        const int rl  = w * 4 + rr;       // local row 0..15
        const int row = g * 16 + rl;
        float4 v = ((const float4*)(x + (size_t)row * D))[lane];
        float s = v.x * v.x + v.y * v.y + v.z * v.z + v.w * v.w;
        #pragma unroll
        for (int off = 32; off; off >>= 1) s += __shfl_down(s, off);
        s = __shfl(s, 0);
        const float inv = 1.0f / fmaxf(sqrtf(s), 1e-12f);
        ushort4 b;
        b.x = f2bf(v.x * inv); b.y = f2bf(v.y * inv);
        b.z = f2bf(v.z * inv); b.w = f2bf(v.w * inv);
        *(ushort4*)(&lnorm[rl][lane * 4]) = b;
    }
    __syncthreads();
    // write tiled: thread t covers chunk kk = t>>5, two lane-slots p = (t&31)*2 + {0,1}
    const int kk = t >> 5;
    const int pp = (t & 31) * 2;
    ushort* base = fn16t + ((size_t)g * 8 + kk) * 512;
    #pragma unroll
    for (int e = 0; e < 2; e++) {
        const int p    = pp + e;
        const int quad = p >> 4;
        const int l15  = p & 15;
        *(short8*)(base + p * 8) = *(const short8*)(&lnorm[l15][kk * 32 + quad * 8]);
    }
}

// ---------------- Kernel 2: triangular MFMA gram, LDS-staged double-buffered K-loop ----------
// R1 change vs proven barrier-free loop (43.4us): the 4 waves duplicated every fragment 2x from
// L2 (256KB/block) and stalled on L2 latency at 3 waves/SIMD (~19% implied MfmaUtil). Now the
// block cooperatively stages the unique 16 chunks/step (16KB) via global_load_lds(16B) into a
// double-buffered LDS, raw s_barrier + counted vmcnt(4) keeps next-step loads in flight across
// the barrier (m97/T3 structure: 16 MFMA + 8 ds_read_b128 + 4 gload_lds per wave per step).
// Stage buffers (32KB) union'd with epilogue rT (34.8KB) -> LDS 36.9KB, still 3 blocks/CU.
__global__ __launch_bounds__(256, 3) void gram_kernel(const ushort* __restrict__ fn16t,
                                                      const int* __restrict__ lab,
                                                      float* __restrict__ gp_part,
                                                      float* __restrict__ gn_part) {
    __shared__ union {
        ushort sbuf[2][8192];              // 2 x 16KB staging (16 chunks x 512 ushorts)
        float  rT[4][BT][17];              // 34816 B epilogue transpose (after final barrier)
    } u;
    __shared__ float cGp[BT][2], cGn[BT][2];   // j-col partials, per wi half

    // XCD swizzle then triangular decode (row-major over jb >= ib)
    const int bidx = blockIdx.x;
    const int idx  = (bidx & 7) * 260 + (bidx >> 3);
    const float c = 2.0f * NJB + 1.0f;
    int ib = (int)((c - sqrtf(c * c - 8.0f * (float)idx)) * 0.5f);
    while (ib > 0 && idx < ib * NJB - ib * (ib - 1) / 2) ib--;
    while (idx >= (ib + 1) * NJB - (ib + 1) * ib / 2) ib++;
    const int jb = ib + (idx - (ib * NJB - ib * (ib - 1) / 2));
    const bool offdiag = (jb > ib);
    const int i0 = ib * BT, j0 = jb * BT;

    const int t    = threadIdx.x;
    const int w    = t >> 6;
    const int lane = t & 63;
    const int wi   = w >> 1, wj = w & 1;        // 2x2 waves, each 64x64
    const int quad = lane >> 4;
    const int l15  = lane & 15;

    // staging: wave w owns slots w*4..w*4+3 (slots 0-7 = A row-groups, 8-15 = B row-groups)
    const int s0 = w * 4;
    const ushort* gsrc[4];
    #pragma unroll
    for (int cc = 0; cc < 4; cc++) {
        const int s = s0 + cc;
        const int gchunk = (s < 8) ? (ib * 8 + s) : (jb * 8 + (s - 8));
        gsrc[cc] = fn16t + (size_t)gchunk * 4096 + lane * 8;
    }
    // compute-side LDS slots for this wave
    const int aslot = wi * 4;
    const int bslot = 8 + wj * 4;

    floatx4 acc[4][4];
    #pragma unroll
    for (int m = 0; m < 4; m++)
        #pragma unroll
        for (int n = 0; n < 4; n++)
            acc[m][n] = (floatx4){0.f, 0.f, 0.f, 0.f};

    // prologue: stage step 0 into buf 0
    #pragma unroll
    for (int cc = 0; cc < 4; cc++)
        gload_lds16(gsrc[cc], &u.sbuf[0][(s0 + cc) * 512]);

    // K-loop: 8 steps of K=32. Stage kk+1 (buf (kk+1)&1), wait counted vmcnt for buf kk, compute.
    #pragma unroll
    for (int kk = 0; kk < 8; kk++) {
        if (kk < 7) {
            #pragma unroll
            for (int cc = 0; cc < 4; cc++)
                gload_lds16(gsrc[cc] + (kk + 1) * 512, &u.sbuf[(kk + 1) & 1][(s0 + cc) * 512]);
            WAITVM(4);                      // buf kk's 4 loads (older) landed; 4 stay in flight
        } else {
            WAITVM(0);                      // last step: drain stage(7)
        }
        BARRIER();                          // all waves' buf-kk data visible

        short8 af[4], bf_[4];
        #pragma unroll
        for (int m = 0; m < 4; m++)
            af[m]  = *(const short8*)&u.sbuf[kk & 1][(aslot + m) * 512 + lane * 8];
        #pragma unroll
        for (int n = 0; n < 4; n++)
            bf_[n] = *(const short8*)&u.sbuf[kk & 1][(bslot + n) * 512 + lane * 8];
        #pragma unroll
        for (int m = 0; m < 4; m++)
            #pragma unroll
            for (int n = 0; n < 4; n++)
                acc[m][n] = __builtin_amdgcn_mfma_f32_16x16x32_bf16(af[m], bf_[n], acc[m][n], 0, 0, 0);

        BARRIER();                          // all waves done reading buf kk before it's re-staged
    }

    // ---- epilogue on g. C/D layout: col = l15 (tile col wj*64+n*16+l15), row = quad*4 + reg.
    int labj[4];
    #pragma unroll
    for (int n = 0; n < 4; n++) labj[n] = lab[j0 + wj * 64 + n * 16 + l15];
    float gpc[4], gnc[4];
    #pragma unroll
    for (int n = 0; n < 4; n++) { gpc[n] = INFINITY; gnc[n] = -INFINITY; }

    #pragma unroll
    for (int m = 0; m < 4; m++) {
        const int4 li4 = *(const int4*)(lab + i0 + wi * 64 + m * 16 + quad * 4);
        const int labi[4] = {li4.x, li4.y, li4.z, li4.w};
        #pragma unroll
        for (int r = 0; r < 4; r++) {
            float pr = INFINITY, nr = -INFINITY;
            #pragma unroll
            for (int n = 0; n < 4; n++) {
                const float g = acc[m][n][r];
                const bool same = (labi[r] == labj[n]);
                const float selp = same ? g : INFINITY;
                const float seln = same ? -INFINITY : g;
                pr = fminf(pr, selp);           nr = fmaxf(nr, seln);
                gpc[n] = fminf(gpc[n], selp);   gnc[n] = fmaxf(gnc[n], seln);
            }
            if (offdiag) {                      // row-side: LDS transpose, no shuffle chain
                const int irow = wi * 64 + m * 16 + quad * 4 + r;
                u.rT[(wj << 1) + 0][irow][l15] = pr;
                u.rT[(wj << 1) + 1][irow][l15] = nr;
            }
        }
    }
    // column-side: reduce across 4 quads (covers all 64 rows of the wi half)
    #pragma unroll
    for (int n = 0; n < 4; n++) {
        float p = gpc[n], q2 = gnc[n];
        p  = fminf(p,  __shfl_xor(p, 16));  p  = fminf(p,  __shfl_xor(p, 32));
        q2 = fmaxf(q2, __shfl_xor(q2, 16)); q2 = fmaxf(q2, __shfl_xor(q2, 32));
        if (quad == 0) {
            const int col = wj * 64 + n * 16 + l15;
            cGp[col][wi] = p; cGn[col][wi] = q2;
        }
    }
    __syncthreads();
    if (t < BT) {                               // waves 0-1: column-side store
        gp_part[(size_t)ib * N + j0 + t] = fminf(cGp[t][0], cGp[t][1]);
        gn_part[(size_t)ib * N + j0 + t] = fmaxf(cGn[t][0], cGn[t][1]);
    } else if (offdiag) {                       // waves 2-3: fold rT rows, row-side store
        const int i = t - BT;
        float p = INFINITY, nn = -INFINITY;
        #pragma unroll
        for (int k = 0; k < 16; k++) {
            p  = fminf(p,  fminf(u.rT[0][i][k], u.rT[2][i][k]));
            nn = fmaxf(nn, fmaxf(u.rT[1][i][k], u.rT[3][i][k]));
        }
        gp_part[(size_t)jb * N + i0 + i] = p;
        gn_part[(size_t)jb * N + i0 + i] = nn;
    }
}

// ---------------- Kernel 3: fold slots, sqrt, relu, mean — 256 blocks, coalesced ------------
__global__ __launch_bounds__(256) void reduce_kernel(const float* __restrict__ gp_part,
                                                     const float* __restrict__ gn_part,
                                                     float* __restrict__ out) {
    __shared__ float redp[32][5], redn[32][5];
    const int t  = threadIdx.x;
    const int r  = blockIdx.x * 32 + (t & 31);   // 256 blocks x 32 rows
    const int sg = t >> 5;                        // slot group 0..7
    float gp = INFINITY, gn = -INFINITY;
    #pragma unroll
    for (int q = 0; q < 8; q++) {
        const int s = sg * 8 + q;
        gp = fminf(gp, gp_part[(size_t)s * N + r]);
        gn = fmaxf(gn, gn_part[(size_t)s * N + r]);
    }
    gp = fminf(gp, __shfl_xor(gp, 32));
    gn = fmaxf(gn, __shfl_xor(gn, 32));
    const int w = t >> 6;
    if ((t & 63) < 32) { redp[t & 31][w] = gp; redn[t & 31][w] = gn; }
    __syncthreads();
    if (t < 32) {
        const float p  = fminf(fminf(redp[t][0], redp[t][1]), fminf(redp[t][2], redp[t][3]));
        const float nn = fmaxf(fmaxf(redn[t][0], redn[t][1]), fmaxf(redn[t][2], redn[t][3]));
        const float dp = sqrtf(fmaxf(2.0f - 2.0f * p,  EPS));  // hardest_pos distance
        const float dn = sqrtf(fmaxf(2.0f - 2.0f * nn, EPS));  // hardest_neg distance
        const float l  = dp - dn + MARGIN;
        float sum = (l > 0.0f) ? l : 0.0f;
        #pragma unroll
        for (int off = 16; off; off >>= 1) sum += __shfl_down(sum, off);
        if (t == 0) atomicAdd(out, sum * (1.0f / (float)N));
    }
}

extern "C" void kernel_launch(void* const* d_in, const int* in_sizes, int n_in,
                              void* d_out, int out_size, void* d_ws, size_t ws_size,
                              hipStream_t stream) {
    const float* x   = (const float*)d_in[0];
    const int*   lab = (const int*)d_in[1];
    float* out = (float*)d_out;

    char* ws = (char*)d_ws;
    ushort* fn16t   = (ushort*)ws;                                  // N*D bf16 = 4 MB (tiled)
    float*  gp_part = (float*)(ws + (size_t)N * D * 2);             // NJB*N floats = 2 MB
    float*  gn_part = gp_part + (size_t)NJB * N;                    // NJB*N floats = 2 MB

    normalize_kernel<<<N / 16, 256, 0, stream>>>(x, fn16t, out);
    gram_kernel<<<TOTAL_TRI, 256, 0, stream>>>(fn16t, lab, gp_part, gn_part);
    reduce_kernel<<<N / 32, 256, 0, stream>>>(gp_part, gn_part, out);
}

// Round 3
// 101.146 us; speedup vs baseline: 1.1275x; 1.1275x over previous
//
#include <hip/hip_runtime.h>
#include <hip/hip_bf16.h>
#include <math.h>

#define N 8192
#define D 256
#define MARGIN 0.3f
#define EPS 1e-12f

#define BT 128                             // block tile (i and j)
#define NJB (N / BT)                       // 64 tile-blocks per dim
#define TOTAL_TRI (NJB * (NJB + 1) / 2)    // 2080 upper-triangle tiles = 8 * 260

typedef __attribute__((ext_vector_type(8))) short short8;   // 8 bf16 in 4 VGPRs
typedef __attribute__((ext_vector_type(4))) float floatx4;  // MFMA C/D

static __device__ inline ushort f2bf(float f) {
    __hip_bfloat16 h = __float2bfloat16(f);
    return *reinterpret_cast<ushort*>(&h);
}

// fn16t layout (MFMA-fragment-tiled): element (row r, k) lives at
//   chunk c = (r>>4)*8 + (k>>5), offset (((k>>3)&3)*16 + (r&15))*8 + (k&7)
// so a wave (lane = quad*16+l15) loads fragment (rows g*16..+15, k-step kk) as ONE contiguous
// 1KB transaction: *(short8*)(fn16t + c*512 + lane*8).

// ---------------- Kernel 1: L2 normalize -> bf16 in tiled layout (16 rows/block) -------------
__global__ __launch_bounds__(256) void normalize_kernel(const float* __restrict__ x,
                                                        ushort* __restrict__ fn16t,
                                                        float* __restrict__ out) {
    __shared__ ushort lnorm[16][256];     // 8 KB
    const int g    = blockIdx.x;          // group of 16 rows
    const int t    = threadIdx.x;
    const int w    = t >> 6;
    const int lane = t & 63;
    if (g == 0 && t == 0) out[0] = 0.0f;

    #pragma unroll
    for (int rr = 0; rr < 4; rr++) {
        const int rl  = w * 4 + rr;       // local row 0..15
        const int row = g * 16 + rl;
        float4 v = ((const float4*)(x + (size_t)row * D))[lane];
        float s = v.x * v.x + v.y * v.y + v.z * v.z + v.w * v.w;
        #pragma unroll
        for (int off = 32; off; off >>= 1) s += __shfl_down(s, off);
        s = __shfl(s, 0);
        const float inv = 1.0f / fmaxf(sqrtf(s), 1e-12f);
        ushort4 b;
        b.x = f2bf(v.x * inv); b.y = f2bf(v.y * inv);
        b.z = f2bf(v.z * inv); b.w = f2bf(v.w * inv);
        *(ushort4*)(&lnorm[rl][lane * 4]) = b;
    }
    __syncthreads();
    // write tiled: thread t covers chunk kk = t>>5, two lane-slots p = (t&31)*2 + {0,1}
    const int kk = t >> 5;
    const int pp = (t & 31) * 2;
    ushort* base = fn16t + ((size_t)g * 8 + kk) * 512;
    #pragma unroll
    for (int e = 0; e < 2; e++) {
        const int p    = pp + e;
        const int quad = p >> 4;
        const int l15  = p & 15;
        *(short8*)(base + p * 8) = *(const short8*)(&lnorm[l15][kk * 32 + quad * 8]);
    }
}

// ---------------- Kernel 2: triangular MFMA gram, barrier-free K-loop + rT epilogue ----------
// K-loop = exact proven R0 structure (43.4us: tiled-layout contiguous 1KB fragment loads from
// global, no barriers). R2 change: tile-ORDER only. Old order walked each XCD through 260
// row-major tri tiles -> B-panels swept the full 4MB fn16t per A-row (= one XCD's whole L2) ->
// B reads thrashed to LLC (~12 TB/s effective, 43.4us on a 532MB stream). New order groups the
// triangle into 8x8-tile superblocks, column-band-major (for JB: for IB<=JB), row-major inside.
// Each XCD's contiguous 260-tile run then lives in ~1MB (one 512KB B-band + one 512KB A-band),
// fitting 4MB L2 with headroom; B-band is reused across the whole IB column sweep.
// Reductions on g (post-norm ||f||^2==1, d2=2-2g monotone dec: hardest_pos = min g over
// positives, hardest_neg = max g over negatives). Plain stores, no atomics/fences.
__global__ __launch_bounds__(256, 3) void gram_kernel(const ushort* __restrict__ fn16t,
                                                      const int* __restrict__ lab,
                                                      float* __restrict__ gp_part,
                                                      float* __restrict__ gn_part) {
    __shared__ float rT[4][BT][17];            // 34816 B; plane = wj*2 + {0:p,1:n}
    __shared__ float cGp[BT][2], cGn[BT][2];   // j-col partials, per wi half

    // XCD swizzle: XCD x owns list positions x*260..x*260+259 (contiguous superblock run)
    const int bidx = blockIdx.x;
    int s = (bidx & 7) * 260 + (bidx >> 3);

    // decode list position -> superblock (IB,JB), column-band-major over the 8x8 SB triangle
    int IB = 0, JB = 0;
    for (;;) {
        const int cnt = (IB == JB) ? 36 : 64;   // diag SB holds upper-tri 8x8 = 36 tiles
        if (s < cnt) break;
        s -= cnt;
        if (IB == JB) { JB++; IB = 0; } else IB++;
    }
    int u, v;
    if (IB == JB) {                             // row-major upper-tri within diag SB
        u = 0;
        while (s >= 8 - u) { s -= 8 - u; u++; }
        v = u + s;
    } else {                                    // row-major within off-diag SB
        u = s >> 3; v = s & 7;
    }
    const int ib = IB * 8 + u, jb = JB * 8 + v;
    const bool offdiag = (jb > ib);
    const int i0 = ib * BT, j0 = jb * BT;

    const int t    = threadIdx.x;
    const int w    = t >> 6;
    const int lane = t & 63;
    const int wi   = w >> 1, wj = w & 1;        // 2x2 waves, each 64x64
    const int quad = lane >> 4;
    const int l15  = lane & 15;

    // fragment base pointers into the tiled layout (group stride = 4096 ushorts)
    const ushort* pA[4];
    const ushort* pB[4];
    #pragma unroll
    for (int m = 0; m < 4; m++)
        pA[m] = fn16t + ((size_t)(ib * 8 + wi * 4 + m)) * 4096 + lane * 8;
    #pragma unroll
    for (int n = 0; n < 4; n++)
        pB[n] = fn16t + ((size_t)(jb * 8 + wj * 4 + n)) * 4096 + lane * 8;

    floatx4 acc[4][4];
    #pragma unroll
    for (int m = 0; m < 4; m++)
        #pragma unroll
        for (int n = 0; n < 4; n++)
            acc[m][n] = (floatx4){0.f, 0.f, 0.f, 0.f};

    // K-loop: 8 steps of K=32, contiguous 1KB fragment loads, no barriers
    #pragma unroll
    for (int kk = 0; kk < 8; kk++) {
        short8 af[4], bf_[4];
        #pragma unroll
        for (int m = 0; m < 4; m++) af[m]  = *(const short8*)(pA[m] + kk * 512);
        #pragma unroll
        for (int n = 0; n < 4; n++) bf_[n] = *(const short8*)(pB[n] + kk * 512);
        #pragma unroll
        for (int m = 0; m < 4; m++)
            #pragma unroll
            for (int n = 0; n < 4; n++)
                acc[m][n] = __builtin_amdgcn_mfma_f32_16x16x32_bf16(af[m], bf_[n], acc[m][n], 0, 0, 0);
    }

    // ---- epilogue on g. C/D layout: col = l15 (tile col wj*64+n*16+l15), row = quad*4 + reg.
    int labj[4];
    #pragma unroll
    for (int n = 0; n < 4; n++) labj[n] = lab[j0 + wj * 64 + n * 16 + l15];
    float gpc[4], gnc[4];
    #pragma unroll
    for (int n = 0; n < 4; n++) { gpc[n] = INFINITY; gnc[n] = -INFINITY; }

    #pragma unroll
    for (int m = 0; m < 4; m++) {
        const int4 li4 = *(const int4*)(lab + i0 + wi * 64 + m * 16 + quad * 4);
        const int labi[4] = {li4.x, li4.y, li4.z, li4.w};
        #pragma unroll
        for (int r = 0; r < 4; r++) {
            float pr = INFINITY, nr = -INFINITY;
            #pragma unroll
            for (int n = 0; n < 4; n++) {
                const float g = acc[m][n][r];
                const bool same = (labi[r] == labj[n]);
                const float selp = same ? g : INFINITY;
                const float seln = same ? -INFINITY : g;
                pr = fminf(pr, selp);           nr = fmaxf(nr, seln);
                gpc[n] = fminf(gpc[n], selp);   gnc[n] = fmaxf(gnc[n], seln);
            }
            if (offdiag) {                      // row-side: LDS transpose, no shuffle chain
                const int irow = wi * 64 + m * 16 + quad * 4 + r;
                rT[(wj << 1) + 0][irow][l15] = pr;
                rT[(wj << 1) + 1][irow][l15] = nr;
            }
        }
    }
    // column-side: reduce across 4 quads (covers all 64 rows of the wi half)
    #pragma unroll
    for (int n = 0; n < 4; n++) {
        float p = gpc[n], q2 = gnc[n];
        p  = fminf(p,  __shfl_xor(p, 16));  p  = fminf(p,  __shfl_xor(p, 32));
        q2 = fmaxf(q2, __shfl_xor(q2, 16)); q2 = fmaxf(q2, __shfl_xor(q2, 32));
        if (quad == 0) {
            const int col = wj * 64 + n * 16 + l15;
            cGp[col][wi] = p; cGn[col][wi] = q2;
        }
    }
    __syncthreads();
    if (t < BT) {                               // waves 0-1: column-side store
        gp_part[(size_t)ib * N + j0 + t] = fminf(cGp[t][0], cGp[t][1]);
        gn_part[(size_t)ib * N + j0 + t] = fmaxf(cGn[t][0], cGn[t][1]);
    } else if (offdiag) {                       // waves 2-3: fold rT rows, row-side store
        const int i = t - BT;
        float p = INFINITY, nn = -INFINITY;
        #pragma unroll
        for (int k = 0; k < 16; k++) {
            p  = fminf(p,  fminf(rT[0][i][k], rT[2][i][k]));
            nn = fmaxf(nn, fmaxf(rT[1][i][k], rT[3][i][k]));
        }
        gp_part[(size_t)jb * N + i0 + i] = p;
        gn_part[(size_t)jb * N + i0 + i] = nn;
    }
}

// ---------------- Kernel 3: fold slots, sqrt, relu, mean — 256 blocks, coalesced ------------
__global__ __launch_bounds__(256) void reduce_kernel(const float* __restrict__ gp_part,
                                                     const float* __restrict__ gn_part,
                                                     float* __restrict__ out) {
    __shared__ float redp[32][5], redn[32][5];
    const int t  = threadIdx.x;
    const int r  = blockIdx.x * 32 + (t & 31);   // 256 blocks x 32 rows
    const int sg = t >> 5;                        // slot group 0..7
    float gp = INFINITY, gn = -INFINITY;
    #pragma unroll
    for (int q = 0; q < 8; q++) {
        const int s = sg * 8 + q;
        gp = fminf(gp, gp_part[(size_t)s * N + r]);
        gn = fmaxf(gn, gn_part[(size_t)s * N + r]);
    }
    gp = fminf(gp, __shfl_xor(gp, 32));
    gn = fmaxf(gn, __shfl_xor(gn, 32));
    const int w = t >> 6;
    if ((t & 63) < 32) { redp[t & 31][w] = gp; redn[t & 31][w] = gn; }
    __syncthreads();
    if (t < 32) {
        const float p  = fminf(fminf(redp[t][0], redp[t][1]), fminf(redp[t][2], redp[t][3]));
        const float nn = fmaxf(fmaxf(redn[t][0], redn[t][1]), fmaxf(redn[t][2], redn[t][3]));
        const float dp = sqrtf(fmaxf(2.0f - 2.0f * p,  EPS));  // hardest_pos distance
        const float dn = sqrtf(fmaxf(2.0f - 2.0f * nn, EPS));  // hardest_neg distance
        const float l  = dp - dn + MARGIN;
        float sum = (l > 0.0f) ? l : 0.0f;
        #pragma unroll
        for (int off = 16; off; off >>= 1) sum += __shfl_down(sum, off);
        if (t == 0) atomicAdd(out, sum * (1.0f / (float)N));
    }
}

extern "C" void kernel_launch(void* const* d_in, const int* in_sizes, int n_in,
                              void* d_out, int out_size, void* d_ws, size_t ws_size,
                              hipStream_t stream) {
    const float* x   = (const float*)d_in[0];
    const int*   lab = (const int*)d_in[1];
    float* out = (float*)d_out;

    char* ws = (char*)d_ws;
    ushort* fn16t   = (ushort*)ws;                                  // N*D bf16 = 4 MB (tiled)
    float*  gp_part = (float*)(ws + (size_t)N * D * 2);             // NJB*N floats = 2 MB
    float*  gn_part = gp_part + (size_t)NJB * N;                    // NJB*N floats = 2 MB

    normalize_kernel<<<N / 16, 256, 0, stream>>>(x, fn16t, out);
    gram_kernel<<<TOTAL_TRI, 256, 0, stream>>>(fn16t, lab, gp_part, gn_part);
    reduce_kernel<<<N / 32, 256, 0, stream>>>(gp_part, gn_part, out);
}

// Round 4
// 98.483 us; speedup vs baseline: 1.1580x; 1.0270x over previous
//
#include <hip/hip_runtime.h>
#include <hip/hip_bf16.h>
#include <math.h>

#define N 8192
#define D 256
#define MARGIN 0.3f
#define EPS 1e-12f

#define BT 128                             // block tile (i and j)
#define NJB (N / BT)                       // 64 tile-blocks per dim
#define TOTAL_TRI (NJB * (NJB + 1) / 2)    // 2080 upper-triangle tiles = 8 * 260

typedef __attribute__((ext_vector_type(8))) short short8;   // 8 bf16 in 4 VGPRs
typedef __attribute__((ext_vector_type(4))) float floatx4;  // MFMA C/D

static __device__ inline ushort f2bf(float f) {
    __hip_bfloat16 h = __float2bfloat16(f);
    return *reinterpret_cast<ushort*>(&h);
}

// fn16t layout (MFMA-fragment-tiled): element (row r, k) lives at
//   chunk c = (r>>4)*8 + (k>>5), offset (((k>>3)&3)*16 + (r&15))*8 + (k&7)
// so a wave (lane = quad*16+l15) loads fragment (rows g*16..+15, k-step kk) as ONE contiguous
// 1KB transaction: *(short8*)(fn16t + c*512 + lane*8).

// ---------------- Kernel 1: L2 normalize -> bf16 in tiled layout (16 rows/block) -------------
__global__ __launch_bounds__(256) void normalize_kernel(const float* __restrict__ x,
                                                        ushort* __restrict__ fn16t,
                                                        float* __restrict__ out) {
    __shared__ ushort lnorm[16][256];     // 8 KB
    const int g    = blockIdx.x;          // group of 16 rows
    const int t    = threadIdx.x;
    const int w    = t >> 6;
    const int lane = t & 63;
    if (g == 0 && t == 0) out[0] = 0.0f;

    #pragma unroll
    for (int rr = 0; rr < 4; rr++) {
        const int rl  = w * 4 + rr;       // local row 0..15
        const int row = g * 16 + rl;
        float4 v = ((const float4*)(x + (size_t)row * D))[lane];
        float s = v.x * v.x + v.y * v.y + v.z * v.z + v.w * v.w;
        #pragma unroll
        for (int off = 32; off; off >>= 1) s += __shfl_down(s, off);
        s = __shfl(s, 0);
        const float inv = 1.0f / fmaxf(sqrtf(s), 1e-12f);
        ushort4 b;
        b.x = f2bf(v.x * inv); b.y = f2bf(v.y * inv);
        b.z = f2bf(v.z * inv); b.w = f2bf(v.w * inv);
        *(ushort4*)(&lnorm[rl][lane * 4]) = b;
    }
    __syncthreads();
    // write tiled: thread t covers chunk kk = t>>5, two lane-slots p = (t&31)*2 + {0,1}
    const int kk = t >> 5;
    const int pp = (t & 31) * 2;
    ushort* base = fn16t + ((size_t)g * 8 + kk) * 512;
    #pragma unroll
    for (int e = 0; e < 2; e++) {
        const int p    = pp + e;
        const int quad = p >> 4;
        const int l15  = p & 15;
        *(short8*)(base + p * 8) = *(const short8*)(&lnorm[l15][kk * 32 + quad * 8]);
    }
}

// ---------------- Kernel 2: triangular MFMA gram, reg-double-buffered K-loop + rT epilogue ---
// R4 change (one variable): the proven barrier-free K-loop (43.4us) is latency-bound — each
// step was [8x1KB L2 loads -> wait-all -> 16 MFMA], paying ~500cy L2 latency serially per step
// (R1 staging and R3 reordering both falsified BW/cache theories). Now fragments are double-
// buffered in REGISTERS with two named sets (static indexing): loads for step k+1 issue before
// the MFMAs of step k, so the compiler's auto-waitcnt becomes a counted vmcnt(8) and L2 latency
// hides under compute. No barriers, no LDS in the K-loop. Decode reverted to R0 triangular.
// Reductions on g (post-norm ||f||^2==1, d2=2-2g monotone dec: hardest_pos = min g over
// positives, hardest_neg = max g over negatives). Plain stores, no atomics/fences.
__global__ __launch_bounds__(256, 3) void gram_kernel(const ushort* __restrict__ fn16t,
                                                      const int* __restrict__ lab,
                                                      float* __restrict__ gp_part,
                                                      float* __restrict__ gn_part) {
    __shared__ float rT[4][BT][17];            // 34816 B; plane = wj*2 + {0:p,1:n}
    __shared__ float cGp[BT][2], cGn[BT][2];   // j-col partials, per wi half

    // XCD swizzle then triangular decode (row-major over jb >= ib)
    const int bidx = blockIdx.x;
    const int idx  = (bidx & 7) * 260 + (bidx >> 3);
    const float c = 2.0f * NJB + 1.0f;
    int ib = (int)((c - sqrtf(c * c - 8.0f * (float)idx)) * 0.5f);
    while (ib > 0 && idx < ib * NJB - ib * (ib - 1) / 2) ib--;
    while (idx >= (ib + 1) * NJB - (ib + 1) * ib / 2) ib++;
    const int jb = ib + (idx - (ib * NJB - ib * (ib - 1) / 2));
    const bool offdiag = (jb > ib);
    const int i0 = ib * BT, j0 = jb * BT;

    const int t    = threadIdx.x;
    const int w    = t >> 6;
    const int lane = t & 63;
    const int wi   = w >> 1, wj = w & 1;        // 2x2 waves, each 64x64
    const int quad = lane >> 4;
    const int l15  = lane & 15;

    // fragment base pointers into the tiled layout (group stride = 4096 ushorts)
    const ushort* pA[4];
    const ushort* pB[4];
    #pragma unroll
    for (int m = 0; m < 4; m++)
        pA[m] = fn16t + ((size_t)(ib * 8 + wi * 4 + m)) * 4096 + lane * 8;
    #pragma unroll
    for (int n = 0; n < 4; n++)
        pB[n] = fn16t + ((size_t)(jb * 8 + wj * 4 + n)) * 4096 + lane * 8;

    floatx4 acc[4][4];
    #pragma unroll
    for (int m = 0; m < 4; m++)
        #pragma unroll
        for (int n = 0; n < 4; n++)
            acc[m][n] = (floatx4){0.f, 0.f, 0.f, 0.f};

    // K-loop: 8 steps of K=32, register double-buffer, loads for k+1 issued before MFMAs of k
    short8 a0[4], b0[4], a1[4], b1[4];
    #pragma unroll
    for (int m = 0; m < 4; m++) a0[m] = *(const short8*)(pA[m]);
    #pragma unroll
    for (int n = 0; n < 4; n++) b0[n] = *(const short8*)(pB[n]);

    #pragma unroll
    for (int kk = 0; kk < 8; kk += 2) {
        // issue loads for step kk+1 into set1
        #pragma unroll
        for (int m = 0; m < 4; m++) a1[m] = *(const short8*)(pA[m] + (kk + 1) * 512);
        #pragma unroll
        for (int n = 0; n < 4; n++) b1[n] = *(const short8*)(pB[n] + (kk + 1) * 512);
        // MFMA with set0 (step kk) — waits only on set0's 8 loads (vmcnt counted)
        #pragma unroll
        for (int m = 0; m < 4; m++)
            #pragma unroll
            for (int n = 0; n < 4; n++)
                acc[m][n] = __builtin_amdgcn_mfma_f32_16x16x32_bf16(a0[m], b0[n], acc[m][n], 0, 0, 0);
        // issue loads for step kk+2 into set0
        if (kk + 2 < 8) {
            #pragma unroll
            for (int m = 0; m < 4; m++) a0[m] = *(const short8*)(pA[m] + (kk + 2) * 512);
            #pragma unroll
            for (int n = 0; n < 4; n++) b0[n] = *(const short8*)(pB[n] + (kk + 2) * 512);
        }
        // MFMA with set1 (step kk+1)
        #pragma unroll
        for (int m = 0; m < 4; m++)
            #pragma unroll
            for (int n = 0; n < 4; n++)
                acc[m][n] = __builtin_amdgcn_mfma_f32_16x16x32_bf16(a1[m], b1[n], acc[m][n], 0, 0, 0);
    }

    // ---- epilogue on g. C/D layout: col = l15 (tile col wj*64+n*16+l15), row = quad*4 + reg.
    int labj[4];
    #pragma unroll
    for (int n = 0; n < 4; n++) labj[n] = lab[j0 + wj * 64 + n * 16 + l15];
    float gpc[4], gnc[4];
    #pragma unroll
    for (int n = 0; n < 4; n++) { gpc[n] = INFINITY; gnc[n] = -INFINITY; }

    #pragma unroll
    for (int m = 0; m < 4; m++) {
        const int4 li4 = *(const int4*)(lab + i0 + wi * 64 + m * 16 + quad * 4);
        const int labi[4] = {li4.x, li4.y, li4.z, li4.w};
        #pragma unroll
        for (int r = 0; r < 4; r++) {
            float pr = INFINITY, nr = -INFINITY;
            #pragma unroll
            for (int n = 0; n < 4; n++) {
                const float g = acc[m][n][r];
                const bool same = (labi[r] == labj[n]);
                const float selp = same ? g : INFINITY;
                const float seln = same ? -INFINITY : g;
                pr = fminf(pr, selp);           nr = fmaxf(nr, seln);
                gpc[n] = fminf(gpc[n], selp);   gnc[n] = fmaxf(gnc[n], seln);
            }
            if (offdiag) {                      // row-side: LDS transpose, no shuffle chain
                const int irow = wi * 64 + m * 16 + quad * 4 + r;
                rT[(wj << 1) + 0][irow][l15] = pr;
                rT[(wj << 1) + 1][irow][l15] = nr;
            }
        }
    }
    // column-side: reduce across 4 quads (covers all 64 rows of the wi half)
    #pragma unroll
    for (int n = 0; n < 4; n++) {
        float p = gpc[n], q2 = gnc[n];
        p  = fminf(p,  __shfl_xor(p, 16));  p  = fminf(p,  __shfl_xor(p, 32));
        q2 = fmaxf(q2, __shfl_xor(q2, 16)); q2 = fmaxf(q2, __shfl_xor(q2, 32));
        if (quad == 0) {
            const int col = wj * 64 + n * 16 + l15;
            cGp[col][wi] = p; cGn[col][wi] = q2;
        }
    }
    __syncthreads();
    if (t < BT) {                               // waves 0-1: column-side store
        gp_part[(size_t)ib * N + j0 + t] = fminf(cGp[t][0], cGp[t][1]);
        gn_part[(size_t)ib * N + j0 + t] = fmaxf(cGn[t][0], cGn[t][1]);
    } else if (offdiag) {                       // waves 2-3: fold rT rows, row-side store
        const int i = t - BT;
        float p = INFINITY, nn = -INFINITY;
        #pragma unroll
        for (int k = 0; k < 16; k++) {
            p  = fminf(p,  fminf(rT[0][i][k], rT[2][i][k]));
            nn = fmaxf(nn, fmaxf(rT[1][i][k], rT[3][i][k]));
        }
        gp_part[(size_t)jb * N + i0 + i] = p;
        gn_part[(size_t)jb * N + i0 + i] = nn;
    }
}

// ---------------- Kernel 3: fold slots, sqrt, relu, mean — 256 blocks, coalesced ------------
__global__ __launch_bounds__(256) void reduce_kernel(const float* __restrict__ gp_part,
                                                     const float* __restrict__ gn_part,
                                                     float* __restrict__ out) {
    __shared__ float redp[32][5], redn[32][5];
    const int t  = threadIdx.x;
    const int r  = blockIdx.x * 32 + (t & 31);   // 256 blocks x 32 rows
    const int sg = t >> 5;                        // slot group 0..7
    float gp = INFINITY, gn = -INFINITY;
    #pragma unroll
    for (int q = 0; q < 8; q++) {
        const int s = sg * 8 + q;
        gp = fminf(gp, gp_part[(size_t)s * N + r]);
        gn = fmaxf(gn, gn_part[(size_t)s * N + r]);
    }
    gp = fminf(gp, __shfl_xor(gp, 32));
    gn = fmaxf(gn, __shfl_xor(gn, 32));
    const int w = t >> 6;
    if ((t & 63) < 32) { redp[t & 31][w] = gp; redn[t & 31][w] = gn; }
    __syncthreads();
    if (t < 32) {
        const float p  = fminf(fminf(redp[t][0], redp[t][1]), fminf(redp[t][2], redp[t][3]));
        const float nn = fmaxf(fmaxf(redn[t][0], redn[t][1]), fmaxf(redn[t][2], redn[t][3]));
        const float dp = sqrtf(fmaxf(2.0f - 2.0f * p,  EPS));  // hardest_pos distance
        const float dn = sqrtf(fmaxf(2.0f - 2.0f * nn, EPS));  // hardest_neg distance
        const float l  = dp - dn + MARGIN;
        float sum = (l > 0.0f) ? l : 0.0f;
        #pragma unroll
        for (int off = 16; off; off >>= 1) sum += __shfl_down(sum, off);
        if (t == 0) atomicAdd(out, sum * (1.0f / (float)N));
    }
}

extern "C" void kernel_launch(void* const* d_in, const int* in_sizes, int n_in,
                              void* d_out, int out_size, void* d_ws, size_t ws_size,
                              hipStream_t stream) {
    const float* x   = (const float*)d_in[0];
    const int*   lab = (const int*)d_in[1];
    float* out = (float*)d_out;

    char* ws = (char*)d_ws;
    ushort* fn16t   = (ushort*)ws;                                  // N*D bf16 = 4 MB (tiled)
    float*  gp_part = (float*)(ws + (size_t)N * D * 2);             // NJB*N floats = 2 MB
    float*  gn_part = gp_part + (size_t)NJB * N;                    // NJB*N floats = 2 MB

    normalize_kernel<<<N / 16, 256, 0, stream>>>(x, fn16t, out);
    gram_kernel<<<TOTAL_TRI, 256, 0, stream>>>(fn16t, lab, gp_part, gn_part);
    reduce_kernel<<<N / 32, 256, 0, stream>>>(gp_part, gn_part, out);
}